// Round 1
// baseline (29.434 us; speedup 1.0000x reference)
//
#include <hip/hip_runtime.h>
#include <math.h>

#define BB 64
#define LL 131072
#define NF 8
#define FLEN 31
#define PADW 15

#define TPB 256
#define RPT 16               // outputs per thread
#define TILE (TPB * RPT)     // 4096 outputs per block

__global__ __launch_bounds__(TPB) void adaptive_filter_fused(
    const float* __restrict__ x,
    const float* __restrict__ features,
    const float* __restrict__ fp,      // (NF, 1, FLEN)
    const float* __restrict__ W1,
    const float* __restrict__ b1,
    const float* __restrict__ W2,
    const float* __restrict__ b2,
    float* __restrict__ out)
{
    const int tiles_per_row = LL / TILE;            // 32
    const int row  = blockIdx.x / tiles_per_row;    // batch index
    const int tile = blockIdx.x % tiles_per_row;

    __shared__ float cs[32];

    // ---- first 31 lanes: compute per-batch effective 31-tap filter ----
    if (threadIdx.x < FLEN) {
        const int t = threadIdx.x;
        float f[NF];
        #pragma unroll
        for (int j = 0; j < NF; ++j) f[j] = features[row * NF + j];

        float h[NF];
        #pragma unroll
        for (int i = 0; i < NF; ++i) {
            float s = b1[i];
            #pragma unroll
            for (int j = 0; j < NF; ++j) s = fmaf(f[j], W1[i * NF + j], s);
            h[i] = fmaxf(s, 0.0f);
        }

        float w[NF];
        float m = -1e30f;
        #pragma unroll
        for (int i = 0; i < NF; ++i) {
            float s = b2[i];
            #pragma unroll
            for (int j = 0; j < NF; ++j) s = fmaf(h[j], W2[i * NF + j], s);
            w[i] = s;
            m = fmaxf(m, s);
        }
        float denom = 0.0f;
        #pragma unroll
        for (int i = 0; i < NF; ++i) { w[i] = expf(w[i] - m); denom += w[i]; }
        const float inv = 1.0f / denom;

        float s = 0.0f;
        #pragma unroll
        for (int ff = 0; ff < NF; ++ff) s = fmaf(w[ff] * inv, fp[ff * FLEN + t], s);
        cs[t] = s;
    }
    __syncthreads();

    // ---- broadcast taps into registers ----
    float c[FLEN];
    #pragma unroll
    for (int t = 0; t < FLEN; ++t) c[t] = cs[t];

    const float* xrow = x + (size_t)row * LL;
    float* orow = out + (size_t)row * LL;

    const int o0 = tile * TILE + threadIdx.x * RPT;  // first output this thread owns
    const int g0 = o0 - 16;                          // window base, 16-float (64B) aligned

    // ---- load 48-float window as 12 aligned float4 (zero-fill outside row) ----
    float win[48];
    #pragma unroll
    for (int k = 0; k < 12; ++k) {
        const int g = g0 + 4 * k;
        float4 v;
        if (g >= 0 && g + 4 <= LL) {
            v = *reinterpret_cast<const float4*>(xrow + g);
        } else {
            v = make_float4(0.0f, 0.0f, 0.0f, 0.0f);
        }
        win[4 * k + 0] = v.x; win[4 * k + 1] = v.y;
        win[4 * k + 2] = v.z; win[4 * k + 3] = v.w;
    }

    // out[o0+r] = sum_t c[t] * x[o0 + r + t - 15]; window index = r + t + 1
    float acc[RPT];
    #pragma unroll
    for (int r = 0; r < RPT; ++r) {
        float s = 0.0f;
        #pragma unroll
        for (int t = 0; t < FLEN; ++t) s = fmaf(c[t], win[r + t + 1], s);
        acc[r] = s;
    }

    #pragma unroll
    for (int r = 0; r < RPT; r += 4) {
        *reinterpret_cast<float4*>(orow + o0 + r) =
            make_float4(acc[r], acc[r + 1], acc[r + 2], acc[r + 3]);
    }
}

extern "C" void kernel_launch(void* const* d_in, const int* in_sizes, int n_in,
                              void* d_out, int out_size, void* d_ws, size_t ws_size,
                              hipStream_t stream) {
    const float* x        = (const float*)d_in[0];
    const float* features = (const float*)d_in[1];
    const float* fp       = (const float*)d_in[2];
    const float* W1       = (const float*)d_in[3];
    const float* b1       = (const float*)d_in[4];
    const float* W2       = (const float*)d_in[5];
    const float* b2       = (const float*)d_in[6];
    float* out = (float*)d_out;

    const int grid = BB * (LL / TILE);  // 64 * 32 = 2048 blocks
    adaptive_filter_fused<<<grid, TPB, 0, stream>>>(x, features, fp, W1, b1, W2, b2, out);
}

// Round 2
// 24.365 us; speedup vs baseline: 1.2080x; 1.2080x over previous
//
#include <hip/hip_runtime.h>
#include <math.h>

#define BB 64
#define LL 131072
#define NF 8
#define FLEN 31

#define TPB 256
#define RPT 16                    // outputs per thread
#define TILE (TPB * RPT)          // 4096 outputs per block
#define NCELLS (TILE / 4 + 8)     // 1032 staged float4 cells (covers [-16, +4112) floats)

// XOR swizzle on float4-cell index: involution, spreads both dense (c=C0+l)
// and strided (c=4l+k) wave patterns evenly across the 8 bank-groups.
#define SWZ(c) ((c) ^ (((c) >> 3) & 7))

__global__ __launch_bounds__(TPB) void adaptive_filter_fused(
    const float* __restrict__ x,
    const float* __restrict__ features,
    const float* __restrict__ fp,      // (NF, 1, FLEN)
    const float* __restrict__ W1,
    const float* __restrict__ b1,
    const float* __restrict__ W2,
    const float* __restrict__ b2,
    float* __restrict__ out)
{
    const int tiles_per_row = LL / TILE;            // 32
    const int row  = blockIdx.x / tiles_per_row;    // batch index
    const int tile = blockIdx.x % tiles_per_row;

    __shared__ float4 lds[NCELLS];                  // 16.5 KB, reused for output
    __shared__ float cs[32];

    const float4* xrow4 = reinterpret_cast<const float4*>(x + (size_t)row * LL);

    // ---- stage x window into LDS: dense coalesced float4 loads, swizzled placement ----
    // cell c holds row-float4 index (tile*1024 - 4 + c); zero-fill outside row.
    const int cell_base = tile * (TILE / 4) - 4;
    for (int c = threadIdx.x; c < NCELLS; c += TPB) {
        const int gc = cell_base + c;
        float4 v = make_float4(0.0f, 0.0f, 0.0f, 0.0f);
        if (gc >= 0 && gc < LL / 4) v = xrow4[gc];
        lds[SWZ(c)] = v;
    }

    // ---- first 31 lanes: per-batch effective 31-tap filter ----
    if (threadIdx.x < FLEN) {
        const int t = threadIdx.x;
        float f[NF];
        #pragma unroll
        for (int j = 0; j < NF; ++j) f[j] = features[row * NF + j];

        float h[NF];
        #pragma unroll
        for (int i = 0; i < NF; ++i) {
            float s = b1[i];
            #pragma unroll
            for (int j = 0; j < NF; ++j) s = fmaf(f[j], W1[i * NF + j], s);
            h[i] = fmaxf(s, 0.0f);
        }

        float w[NF];
        float m = -1e30f;
        #pragma unroll
        for (int i = 0; i < NF; ++i) {
            float s = b2[i];
            #pragma unroll
            for (int j = 0; j < NF; ++j) s = fmaf(h[j], W2[i * NF + j], s);
            w[i] = s;
            m = fmaxf(m, s);
        }
        float denom = 0.0f;
        #pragma unroll
        for (int i = 0; i < NF; ++i) { w[i] = expf(w[i] - m); denom += w[i]; }
        const float inv = 1.0f / denom;

        float s = 0.0f;
        #pragma unroll
        for (int ff = 0; ff < NF; ++ff) s = fmaf(w[ff] * inv, fp[ff * FLEN + t], s);
        cs[t] = s;
    }
    __syncthreads();

    // ---- taps into registers (broadcast, conflict-free) ----
    float tap[FLEN];
    #pragma unroll
    for (int t = 0; t < FLEN; ++t) tap[t] = cs[t];

    // ---- LDS -> 48-float register window (swizzled cells 4i..4i+11) ----
    const int i0 = (int)threadIdx.x;
    float win[48];
    #pragma unroll
    for (int k = 0; k < 12; ++k) {
        const float4 v = lds[SWZ(4 * i0 + k)];
        win[4 * k + 0] = v.x; win[4 * k + 1] = v.y;
        win[4 * k + 2] = v.z; win[4 * k + 3] = v.w;
    }

    // out[o0+r] = sum_t tap[t] * x[o0 + r + t - 15]; window index = r + t + 1
    float acc[RPT];
    #pragma unroll
    for (int r = 0; r < RPT; ++r) {
        float s = 0.0f;
        #pragma unroll
        for (int t = 0; t < FLEN; ++t) s = fmaf(tap[t], win[r + t + 1], s);
        acc[r] = s;
    }

    // ---- route results through LDS so global stores are dense coalesced ----
    __syncthreads();   // all window reads complete before overwrite
    #pragma unroll
    for (int r = 0; r < RPT; r += 4) {
        lds[SWZ(4 * i0 + r / 4)] =
            make_float4(acc[r], acc[r + 1], acc[r + 2], acc[r + 3]);
    }
    __syncthreads();

    float4* orow4 = reinterpret_cast<float4*>(out + (size_t)row * LL) + tile * (TILE / 4);
    #pragma unroll
    for (int m = 0; m < 4; ++m) {
        const int c = (int)threadIdx.x + TPB * m;
        orow4[c] = lds[SWZ(c)];
    }
}

extern "C" void kernel_launch(void* const* d_in, const int* in_sizes, int n_in,
                              void* d_out, int out_size, void* d_ws, size_t ws_size,
                              hipStream_t stream) {
    const float* x        = (const float*)d_in[0];
    const float* features = (const float*)d_in[1];
    const float* fp       = (const float*)d_in[2];
    const float* W1       = (const float*)d_in[3];
    const float* b1       = (const float*)d_in[4];
    const float* W2       = (const float*)d_in[5];
    const float* b2       = (const float*)d_in[6];
    float* out = (float*)d_out;

    const int grid = BB * (LL / TILE);  // 64 * 32 = 2048 blocks
    adaptive_filter_fused<<<grid, TPB, 0, stream>>>(x, features, fp, W1, b1, W2, b2, out);
}

// Round 3
// 21.767 us; speedup vs baseline: 1.3522x; 1.1194x over previous
//
#include <hip/hip_runtime.h>
#include <math.h>

#define BB 64
#define LL 131072
#define NF 8
#define FLEN 31

#define TPB 256
#define RPT 8
#define TILE (TPB * RPT)        // 2048 outputs per block
#define TCELLS (TILE / 4)       // 512 float4 cells per tile
#define NCELLS (TCELLS + 8)     // 520 staged cells (halo 4 each side)
#define ROWCELLS (LL / 4)       // 32768 cells per row

// XOR swizzle on float4-cell index (involution, within-64-cell groups):
// dense writes (c = base+l) and strided reads (c = 2l+const) both spread
// uniformly: 8 lanes per 4-bank group = conflict-free for b128.
#define SWZ(c) ((c) ^ (((c) >> 3) & 7))

__global__ __launch_bounds__(TPB, 6) void adaptive_filter_fused(
    const float* __restrict__ x,
    const float* __restrict__ features,
    const float* __restrict__ fp,      // (NF, 1, FLEN)
    const float* __restrict__ W1,
    const float* __restrict__ b1,
    const float* __restrict__ W2,
    const float* __restrict__ b2,
    float* __restrict__ out)
{
    const int tiles_per_row = LL / TILE;            // 64
    const int row  = blockIdx.x / tiles_per_row;
    const int tile = blockIdx.x % tiles_per_row;
    const int tid  = threadIdx.x;

    __shared__ float4 lds4[NCELLS];                 // 8.3 KB
    __shared__ float cs[32];

    const float4* xrow4 = reinterpret_cast<const float4*>(x + (size_t)row * LL);
    const int cell_base = tile * TCELLS - 4;

    // ---- issue staging loads into regs early (zero-fill outside row) ----
    const int d0 = tid, d1 = tid + TPB, d2 = tid + 2 * TPB;
    const unsigned gc0 = (unsigned)(cell_base + d0);
    const unsigned gc1 = (unsigned)(cell_base + d1);
    const unsigned gc2 = (unsigned)(cell_base + d2);
    float4 v0 = make_float4(0.f, 0.f, 0.f, 0.f);
    float4 v1 = v0, v2 = v0;
    if (gc0 < ROWCELLS) v0 = xrow4[gc0];
    if (gc1 < ROWCELLS) v1 = xrow4[gc1];
    const bool has2 = (tid < NCELLS - 2 * TPB);     // 8 threads
    if (has2 && gc2 < ROWCELLS) v2 = xrow4[gc2];

    // ---- taps MLP on lanes < 31 (overlaps global-load latency) ----
    if (tid < FLEN) {
        const int t = tid;
        float f[NF];
        #pragma unroll
        for (int j = 0; j < NF; ++j) f[j] = features[row * NF + j];

        float h[NF];
        #pragma unroll
        for (int i = 0; i < NF; ++i) {
            float s = b1[i];
            #pragma unroll
            for (int j = 0; j < NF; ++j) s = fmaf(f[j], W1[i * NF + j], s);
            h[i] = fmaxf(s, 0.0f);
        }

        float w[NF];
        float m = -1e30f;
        #pragma unroll
        for (int i = 0; i < NF; ++i) {
            float s = b2[i];
            #pragma unroll
            for (int j = 0; j < NF; ++j) s = fmaf(h[j], W2[i * NF + j], s);
            w[i] = s;
            m = fmaxf(m, s);
        }
        float denom = 0.0f;
        #pragma unroll
        for (int i = 0; i < NF; ++i) { w[i] = expf(w[i] - m); denom += w[i]; }
        const float inv = 1.0f / denom;

        float s = 0.0f;
        #pragma unroll
        for (int ff = 0; ff < NF; ++ff) s = fmaf(w[ff] * inv, fp[ff * FLEN + t], s);
        cs[t] = s;
    }
    if (tid == FLEN) cs[FLEN] = 0.0f;

    // ---- LDS staging writes (swizzled placement) ----
    lds4[SWZ(d0)] = v0;
    lds4[SWZ(d1)] = v1;
    if (has2) lds4[SWZ(d2)] = v2;

    __syncthreads();

    // ---- taps to SGPRs: one broadcast read + 31 readlane ----
    const float tv = cs[tid & 31];
    float tap[FLEN];
    #pragma unroll
    for (int t = 0; t < FLEN; ++t)
        tap[t] = __int_as_float(__builtin_amdgcn_readlane(__float_as_int(tv), t));

    // ---- window: 10 swizzled b128 reads -> 40 floats, two halves ----
    // w[j] = x[row, tile*2048 + 8*tid - 16 + j],  j = 0..39
    float wA[20], wB[20];
    #pragma unroll
    for (int k = 0; k < 5; ++k) {
        const float4 v = lds4[SWZ(2 * tid + k)];
        wA[4 * k + 0] = v.x; wA[4 * k + 1] = v.y;
        wA[4 * k + 2] = v.z; wA[4 * k + 3] = v.w;
    }
    #pragma unroll
    for (int k = 0; k < 5; ++k) {
        const float4 v = lds4[SWZ(2 * tid + 5 + k)];
        wB[4 * k + 0] = v.x; wB[4 * k + 1] = v.y;
        wB[4 * k + 2] = v.z; wB[4 * k + 3] = v.w;
    }

    // out[8*tid + r] = sum_t tap[t] * w[r + 1 + t]
    float acc[RPT];
    #pragma unroll
    for (int r = 0; r < RPT; ++r) acc[r] = 0.0f;

    #pragma unroll
    for (int r = 0; r < RPT; ++r) {
        #pragma unroll
        for (int t = 0; t <= 18 - r; ++t)          // j = r+1+t <= 19
            acc[r] = fmaf(tap[t], wA[r + 1 + t], acc[r]);
        #pragma unroll
        for (int t = 19 - r; t < FLEN; ++t)        // j-20 = r+t-19 in [0, r+11]
            acc[r] = fmaf(tap[t], wB[r + t - 19], acc[r]);
    }

    // ---- direct stores: two float4 per thread (32B lane stride) ----
    float4* orow4 = reinterpret_cast<float4*>(out + (size_t)row * LL) + tile * TCELLS;
    orow4[2 * tid + 0] = make_float4(acc[0], acc[1], acc[2], acc[3]);
    orow4[2 * tid + 1] = make_float4(acc[4], acc[5], acc[6], acc[7]);
}

extern "C" void kernel_launch(void* const* d_in, const int* in_sizes, int n_in,
                              void* d_out, int out_size, void* d_ws, size_t ws_size,
                              hipStream_t stream) {
    const float* x        = (const float*)d_in[0];
    const float* features = (const float*)d_in[1];
    const float* fp       = (const float*)d_in[2];
    const float* W1       = (const float*)d_in[3];
    const float* b1       = (const float*)d_in[4];
    const float* W2       = (const float*)d_in[5];
    const float* b2       = (const float*)d_in[6];
    float* out = (float*)d_out;

    const int grid = BB * (LL / TILE);  // 64 * 64 = 4096 blocks
    adaptive_filter_fused<<<grid, TPB, 0, stream>>>(x, features, fp, W1, b1, W2, b2, out);
}